// Round 14
// baseline (275.051 us; speedup 1.0000x reference)
//
#include <hip/hip_runtime.h>

#define N_SUM 2048
#define HIDD 128
#define NEDGE 16384
#define ROWS (N_SUM * 64)
#define NSLOT 16

typedef short short8 __attribute__((ext_vector_type(8)));
typedef float floatx4 __attribute__((ext_vector_type(4)));
typedef unsigned int uint4n __attribute__((ext_vector_type(4)));
typedef unsigned short ushort_t;

__device__ __forceinline__ ushort_t f2bf(float f) {
    unsigned u = __builtin_bit_cast(unsigned, f);
    u += 0x7fffu + ((u >> 16) & 1u);   // RNE
    return (ushort_t)(u >> 16);
}
__device__ __forceinline__ float bf2f(ushort_t h) {
    return __builtin_bit_cast(float, (unsigned)h << 16);
}
__device__ __forceinline__ void unpack8(uint4 v, float* f) {
    f[0] = bf2f(v.x & 0xffff); f[1] = bf2f(v.x >> 16);
    f[2] = bf2f(v.y & 0xffff); f[3] = bf2f(v.y >> 16);
    f[4] = bf2f(v.z & 0xffff); f[5] = bf2f(v.z >> 16);
    f[6] = bf2f(v.w & 0xffff); f[7] = bf2f(v.w >> 16);
}
__device__ __forceinline__ uint4 pack8(const float* f) {
    uint4 v;
    v.x = f2bf(f[0]) | ((unsigned)f2bf(f[1]) << 16);
    v.y = f2bf(f[2]) | ((unsigned)f2bf(f[3]) << 16);
    v.z = f2bf(f[4]) | ((unsigned)f2bf(f[5]) << 16);
    v.w = f2bf(f[6]) | ((unsigned)f2bf(f[7]) << 16);
    return v;
}
__device__ __forceinline__ void nt_store16(const void* src, void* dst) {
    __builtin_nontemporal_store(*(const uint4n*)src, (uint4n*)dst);
}

// ---------------- mega prep (ONE dispatch, 64 blocks x 1024 threads) ----------------
// block 0      : CSR build (batched loads) + LPT order (counting sort by deg desc)
// blocks 1..13 : w1t0 / w2lt / bvec
// blocks 14..61: w21t = W2m @ W1r (B-fragment layout)
// blocks 62..63: zero sums
__global__ __launch_bounds__(1024) void mega_prep(const int* __restrict__ src, const int* __restrict__ dst,
                                                  const float* __restrict__ W1f, const float* __restrict__ W2l,
                                                  const float* __restrict__ b2m, const float* __restrict__ W1r,
                                                  const float* __restrict__ W2m,
                                                  int* __restrict__ irp, int* __restrict__ icol,
                                                  int* __restrict__ order,
                                                  ushort_t* __restrict__ w1t0, ushort_t* __restrict__ w2lt,
                                                  float* __restrict__ bvec, ushort_t* __restrict__ w21t,
                                                  float* __restrict__ sums) {
    __shared__ int sdeg[2048];
    __shared__ int scur[2048];
    __shared__ int red[1024];
    __shared__ int hist[64];
    int tid = threadIdx.x, blk = blockIdx.x;

    if (blk == 0) {
        sdeg[tid] = 0;
        sdeg[tid + 1024] = 0;
        if (tid < 64) hist[tid] = 0;
        __syncthreads();
        int d[16];
#pragma unroll
        for (int q = 0; q < 16; q++) d[q] = dst[q * 1024 + tid];
#pragma unroll
        for (int q = 0; q < 16; q++) atomicAdd(&sdeg[d[q]], 1);
        __syncthreads();
        int a = sdeg[2 * tid], b = sdeg[2 * tid + 1];
        red[tid] = a + b;
        // degree histogram for LPT counting sort
        atomicAdd(&hist[a & 63], 1);
        atomicAdd(&hist[b & 63], 1);
        __syncthreads();
        for (int off = 1; off < 1024; off <<= 1) {
            int v = (tid >= off) ? red[tid - off] : 0;
            __syncthreads();
            red[tid] += v;
            __syncthreads();
        }
        int base = (tid == 0) ? 0 : red[tid - 1];
        irp[2 * tid] = base;
        irp[2 * tid + 1] = base + a;
        scur[2 * tid] = base;
        scur[2 * tid + 1] = base + a;
        if (tid == 1023) irp[2048] = red[1023];
        __syncthreads();
        int s[16];
#pragma unroll
        for (int q = 0; q < 16; q++) s[q] = src[q * 1024 + tid];
#pragma unroll
        for (int q = 0; q < 16; q++) {
            int pos = atomicAdd(&scur[d[q]], 1);
            icol[pos] = s[q];
        }
        // ---- LPT order: descending-degree start offsets (serial 64-scan on lane 0) ----
        if (tid == 0) {
            int acc = 0;
            for (int bb = 63; bb >= 0; bb--) { int h = hist[bb]; hist[bb] = acc; acc += h; }
        }
        __syncthreads();
        {
            int p1 = atomicAdd(&hist[a & 63], 1);
            order[p1] = 2 * tid;
            int p2 = atomicAdd(&hist[b & 63], 1);
            order[p2] = 2 * tid + 1;
        }
    } else if (blk <= 13) {
        int idx = (blk - 1) * 1024 + tid;
        if (idx < 4096) {
            int nn = idx >> 5, k = idx & 31;
            w1t0[idx] = f2bf(k < 16 ? W1f[k * 128 + nn] : 0.f);
        } else if (idx < 4096 + 8192) {
            int r = idx - 4096;
            int nn = r >> 7, k = r & 127;
            w2lt[r] = f2bf(W2l[k * 64 + nn]);
        } else if (idx < 4096 + 8192 + 384) {
            int r = idx - 12288;
            int lm = r >> 7, c = r & 127;
            float s = 0.f;
            for (int o = 0; o < 128; o++) s += b2m[lm * 128 + o] * W1r[(size_t)lm * 16384 + o * 128 + c];
            bvec[r] = s;
        }
    } else if (blk <= 61) {
        int idx = (blk - 14) * 1024 + tid;  // 49152 total
        int lm = idx >> 14, r = idx & 16383, i = r >> 7, c = r & 127;
        const float* w2row = W2m + (size_t)lm * 16384 + i * 128;
        const float* w1col = W1r + (size_t)lm * 16384 + c;
        float s = 0.f;
#pragma unroll 8
        for (int o = 0; o < 128; o++) s += w2row[o] * w1col[o * 128];
        w21t[(size_t)lm * 16384 + c * 128 + i] = f2bf(s);
    } else {
        int idx = (blk - 62) * 1024 + tid;  // 2048 threads x 8 = 16384
#pragma unroll
        for (int q = 0; q < 8; q++) sums[idx * 8 + q] = 0.f;
    }
}

// A-layout for a 64x128 (or 64x32) bf16 tile: elem(m, k) at ((k>>3)*64 + m)*8 + (k&7)

// ---------------- layer 0: gather fp32 W + MFMA (K=16 padded to 32) ----------------
__global__ __launch_bounds__(256, 4) void gin_mm1_l0(const float* __restrict__ Xf, const ushort_t* __restrict__ W1t,
                                                     const float* __restrict__ b1, const float* __restrict__ eps,
                                                     const int* __restrict__ rp, const int* __restrict__ colv,
                                                     const int* __restrict__ order,
                                                     ushort_t* __restrict__ H, float* __restrict__ sums) {
    __shared__ ushort_t Zs[64 * 128];  // 16 KB
    int tid = threadIdx.x, n = order[blockIdx.x];
    float ev = 1.0f + eps[0];
    int e0 = rp[n], e1 = rp[n + 1], deg = e1 - e0;
    const float4* X = (const float4*)Xf;

    float4 sA, sB;
    sA = X[(size_t)n * 256 + tid];
    if (deg > 0) sB = X[(size_t)colv[e0] * 256 + tid];
    float4 a;
    a.x = sA.x * ev; a.y = sA.y * ev; a.z = sA.z * ev; a.w = sA.w * ev;
    int i = 1;
    for (; i + 1 < deg; i += 2) {
        sA = X[(size_t)colv[e0 + i] * 256 + tid];
        a.x += sB.x; a.y += sB.y; a.z += sB.z; a.w += sB.w;
        sB = X[(size_t)colv[e0 + i + 1] * 256 + tid];
        a.x += sA.x; a.y += sA.y; a.z += sA.z; a.w += sA.w;
    }
    if (deg > 0) {
        if (i < deg) {
            sA = X[(size_t)colv[e0 + i] * 256 + tid];
            a.x += sB.x; a.y += sB.y; a.z += sB.z; a.w += sB.w;
            a.x += sA.x; a.y += sA.y; a.z += sA.z; a.w += sA.w;
        } else {
            a.x += sB.x; a.y += sB.y; a.z += sB.z; a.w += sB.w;
        }
    }

    {
        int m = tid >> 2, k0 = (tid & 3) * 4;
        int addr = ((k0 >> 3) * 64 + m) * 8 + (k0 & 7);
        uint2 pv;
        pv.x = f2bf(a.x) | ((unsigned)f2bf(a.y) << 16);
        pv.y = f2bf(a.z) | ((unsigned)f2bf(a.w) << 16);
        *(uint2*)&Zs[addr] = pv;
        *(uint2*)&Zs[1024 + tid * 4] = make_uint2(0u, 0u);
    }
    __syncthreads();

    int w = tid >> 6, lane = tid & 63, lg = lane >> 4, ln = lane & 15;
    floatx4 C[4][2];
#pragma unroll
    for (int mt = 0; mt < 4; mt++) { C[mt][0] = {0.f, 0.f, 0.f, 0.f}; C[mt][1] = {0.f, 0.f, 0.f, 0.f}; }

    {
        short8 B0 = *(const short8*)&W1t[(w * 32 + ln) * 32 + lg * 8];
        short8 B1 = *(const short8*)&W1t[(w * 32 + 16 + ln) * 32 + lg * 8];
#pragma unroll
        for (int mt = 0; mt < 4; mt++) {
            short8 A = *(const short8*)&Zs[(lg * 64 + mt * 16 + ln) * 8];
            C[mt][0] = __builtin_amdgcn_mfma_f32_16x16x32_bf16(A, B0, C[mt][0], 0, 0, 0);
            C[mt][1] = __builtin_amdgcn_mfma_f32_16x16x32_bf16(A, B1, C[mt][1], 0, 0, 0);
        }
    }

    float bsum[2], bsq[2];
    float bv[2] = {b1[w * 32 + ln], b1[w * 32 + 16 + ln]};
#pragma unroll
    for (int nt = 0; nt < 2; nt++) {
        float s = 0.f, s2 = 0.f;
#pragma unroll
        for (int mt = 0; mt < 4; mt++)
#pragma unroll
            for (int r = 0; r < 4; r++) {
                float v = C[mt][nt][r] + bv[nt];
                C[mt][nt][r] = v;
                s += v; s2 += v * v;
            }
        bsum[nt] = s; bsq[nt] = s2;
    }
#pragma unroll
    for (int nt = 0; nt < 2; nt++) {
        bsum[nt] += __shfl_xor(bsum[nt], 16, 64);
        bsum[nt] += __shfl_xor(bsum[nt], 32, 64);
        bsq[nt] += __shfl_xor(bsq[nt], 16, 64);
        bsq[nt] += __shfl_xor(bsq[nt], 32, 64);
    }
    if (lg == 0) {
        float* sl = sums + (blockIdx.x & (NSLOT - 1)) * 256;
        int c0 = w * 32 + ln;
        atomicAdd(&sl[c0], bsum[0]);
        atomicAdd(&sl[c0 + 16], bsum[1]);
        atomicAdd(&sl[128 + c0], bsq[0]);
        atomicAdd(&sl[128 + c0 + 16], bsq[1]);
    }
    __syncthreads();
#pragma unroll
    for (int nt = 0; nt < 2; nt++) {
        int colc = w * 32 + nt * 16 + ln;
        int base = (colc >> 3) * 512 + (colc & 7);
#pragma unroll
        for (int mt = 0; mt < 4; mt++)
#pragma unroll
            for (int r = 0; r < 4; r++) {
                int row = mt * 16 + lg * 4 + r;
                Zs[base + row * 8] = f2bf(C[mt][nt][r]);
            }
    }
    __syncthreads();
#pragma unroll
    for (int q = 0; q < 4; q++)
        nt_store16(&((const uint4*)Zs)[q * 256 + tid], &((uint4*)&H[(size_t)n * 8192])[q * 256 + tid]);
}

// ---------------- fused layers 1..3 (512 threads, 2-deep pipeline, LPT order) ----------------
__global__ __launch_bounds__(512, 4) void gin_mm1_fused(const ushort_t* __restrict__ Hin,
                                                        const ushort_t* __restrict__ W21t,
                                                        const float* __restrict__ b1, const float* __restrict__ bvec,
                                                        const float* __restrict__ sums_prev,
                                                        const float* __restrict__ gam_prev,
                                                        const float* __restrict__ bet_prev,
                                                        const float* __restrict__ epsp,
                                                        const int* __restrict__ rp, const int* __restrict__ colv,
                                                        const int* __restrict__ order,
                                                        ushort_t* __restrict__ Hout, float* __restrict__ sums_cur) {
    __shared__ ushort_t Zs[64 * 128];   // 16 KB
    __shared__ float scs_lds[256];      // 1 KB
    int tid = threadIdx.x, n = order[blockIdx.x];
    if (tid < 128) {
        float s = 0.f, s2 = 0.f;
#pragma unroll
        for (int k = 0; k < NSLOT; k++) {
            s += sums_prev[k * 256 + tid];
            s2 += sums_prev[k * 256 + 128 + tid];
        }
        float mean = s * (1.f / (float)ROWS);
        float var = s2 * (1.f / (float)ROWS) - mean * mean;
        float sc = gam_prev[tid] * rsqrtf(var + 1e-5f);
        scs_lds[tid] = sc;
        scs_lds[128 + tid] = bet_prev[tid] - mean * sc;
    }
    __syncthreads();

    unsigned scp[2][8];
#pragma unroll
    for (int q = 0; q < 2; q++) {
        int cb = ((q * 512 + tid) >> 6) * 8;
#pragma unroll
        for (int j = 0; j < 8; j++)
            scp[q][j] = ((unsigned)f2bf(scs_lds[cb + j])) | ((unsigned)f2bf(scs_lds[128 + cb + j]) << 16);
    }

    float ev = 1.0f + epsp[0];
    int e0 = rp[n], e1 = rp[n + 1], deg = e1 - e0;
    const uint4* X = (const uint4*)Hin;
    float acc[2][8];
    uint4 bufA[2], bufB[2];

    auto loadslab = [&](uint4* buf, int node) {
        const uint4* p = X + (size_t)node * 1024;
        buf[0] = p[tid];
        buf[1] = p[512 + tid];
    };
    auto addp = [&](const uint4* buf) {
#pragma unroll
        for (int q = 0; q < 2; q++) {
            float f[8]; unpack8(buf[q], f);
#pragma unroll
            for (int j = 0; j < 8; j++) {
                float sc = __builtin_bit_cast(float, scp[q][j] << 16);
                float sh = __builtin_bit_cast(float, scp[q][j] & 0xffff0000u);
                acc[q][j] += fmaxf(fmaf(f[j], sc, sh), 0.f);
            }
        }
    };

    loadslab(bufA, n);
    if (deg > 0) loadslab(bufB, colv[e0]);

#pragma unroll
    for (int q = 0; q < 2; q++) {
        float f[8]; unpack8(bufA[q], f);
#pragma unroll
        for (int j = 0; j < 8; j++) {
            float sc = __builtin_bit_cast(float, scp[q][j] << 16);
            float sh = __builtin_bit_cast(float, scp[q][j] & 0xffff0000u);
            acc[q][j] = ev * fmaxf(fmaf(f[j], sc, sh), 0.f);
        }
    }

    int i = 1;
    for (; i + 1 < deg; i += 2) {
        loadslab(bufA, colv[e0 + i]);
        addp(bufB);
        loadslab(bufB, colv[e0 + i + 1]);
        addp(bufA);
    }
    if (deg > 0) {
        if (i < deg) {
            loadslab(bufA, colv[e0 + i]);
            addp(bufB);
            addp(bufA);
        } else {
            addp(bufB);
        }
    }

#pragma unroll
    for (int q = 0; q < 2; q++) ((uint4*)Zs)[q * 512 + tid] = pack8(acc[q]);
    __syncthreads();

    int w = tid >> 6, lane = tid & 63, lg = lane >> 4, ln = lane & 15;
    floatx4 C[4];
#pragma unroll
    for (int mt = 0; mt < 4; mt++) C[mt] = {0.f, 0.f, 0.f, 0.f};

    for (int kb = 0; kb < 4; kb++) {
        short8 B = *(const short8*)&W21t[(w * 16 + ln) * 128 + kb * 32 + lg * 8];
#pragma unroll
        for (int mt = 0; mt < 4; mt++) {
            short8 A = *(const short8*)&Zs[((kb * 4 + lg) * 64 + mt * 16 + ln) * 8];
            C[mt] = __builtin_amdgcn_mfma_f32_16x16x32_bf16(A, B, C[mt], 0, 0, 0);
        }
    }

    float fac = ev + (float)deg;
    int c0 = w * 16 + ln;
    float bv = b1[c0] + fac * bvec[c0];
    float s = 0.f, s2 = 0.f;
#pragma unroll
    for (int mt = 0; mt < 4; mt++)
#pragma unroll
        for (int r = 0; r < 4; r++) {
            float v = C[mt][r] + bv;
            C[mt][r] = v;
            s += v; s2 += v * v;
        }
    s += __shfl_xor(s, 16, 64);
    s += __shfl_xor(s, 32, 64);
    s2 += __shfl_xor(s2, 16, 64);
    s2 += __shfl_xor(s2, 32, 64);
    if (lg == 0) {
        float* sl = sums_cur + (blockIdx.x & (NSLOT - 1)) * 256;
        atomicAdd(&sl[c0], s);
        atomicAdd(&sl[128 + c0], s2);
    }

    __syncthreads();
    {
        int base = (c0 >> 3) * 512 + (c0 & 7);
#pragma unroll
        for (int mt = 0; mt < 4; mt++)
#pragma unroll
            for (int r = 0; r < 4; r++) {
                int row = mt * 16 + lg * 4 + r;
                Zs[base + row * 8] = f2bf(C[mt][r]);
            }
    }
    __syncthreads();
#pragma unroll
    for (int q = 0; q < 2; q++)
        nt_store16(&((const uint4*)Zs)[q * 512 + tid], &((uint4*)&Hout[(size_t)n * 8192])[q * 512 + tid]);
}

// ---------------- final: PE = sum_rows mask * (relu(bn(H3)) @ W2l + b2l) ----------------
__global__ __launch_bounds__(256, 4) void gin_mm2_last(const ushort_t* __restrict__ H, const ushort_t* __restrict__ W2t,
                                                       const float* __restrict__ b2,
                                                       const float* __restrict__ sums_prev,
                                                       const float* __restrict__ gam_prev,
                                                       const float* __restrict__ bet_prev,
                                                       const float* __restrict__ mask, float* __restrict__ out) {
    __shared__ ushort_t Hs[64 * 128];
    __shared__ float scs_lds[256];
    int tid = threadIdx.x, n = blockIdx.x;
    if (tid < 128) {
        float s = 0.f, s2 = 0.f;
#pragma unroll
        for (int k = 0; k < NSLOT; k++) {
            s += sums_prev[k * 256 + tid];
            s2 += sums_prev[k * 256 + 128 + tid];
        }
        float mean = s * (1.f / (float)ROWS);
        float var = s2 * (1.f / (float)ROWS) - mean * mean;
        float sc = gam_prev[tid] * rsqrtf(var + 1e-5f);
        scs_lds[tid] = sc;
        scs_lds[128 + tid] = bet_prev[tid] - mean * sc;
    }
    __syncthreads();

#pragma unroll
    for (int q = 0; q < 4; q++) {
        int c = q * 256 + tid;
        uint4 v = ((const uint4*)&H[(size_t)n * 8192])[c];
        float f[8]; unpack8(v, f);
        int cb = (c >> 6) * 8;
#pragma unroll
        for (int j = 0; j < 8; j++) f[j] = fmaxf(fmaf(f[j], scs_lds[cb + j], scs_lds[128 + cb + j]), 0.f);
        ((uint4*)Hs)[c] = pack8(f);
    }
    __syncthreads();

    int w = tid >> 6, lane = tid & 63, lg = lane >> 4, ln = lane & 15;
    floatx4 C[4];
#pragma unroll
    for (int mt = 0; mt < 4; mt++) C[mt] = {0.f, 0.f, 0.f, 0.f};

    for (int kb = 0; kb < 4; kb++) {
        short8 B = *(const short8*)&W2t[(w * 16 + ln) * 128 + kb * 32 + lg * 8];
#pragma unroll
        for (int mt = 0; mt < 4; mt++) {
            short8 A = *(const short8*)&Hs[((kb * 4 + lg) * 64 + mt * 16 + ln) * 8];
            C[mt] = __builtin_amdgcn_mfma_f32_16x16x32_bf16(A, B, C[mt], 0, 0, 0);
        }
    }

    int colc = w * 16 + ln;
    float bb = b2[colc];
    float pe = 0.f;
#pragma unroll
    for (int mt = 0; mt < 4; mt++)
#pragma unroll
        for (int r = 0; r < 4; r++) {
            int row = mt * 16 + lg * 4 + r;
            pe += mask[n * 64 + row] * (C[mt][r] + bb);
        }
    pe += __shfl_xor(pe, 16, 64);
    pe += __shfl_xor(pe, 32, 64);
    if (lg == 0) out[(size_t)n * 64 + colc] = pe;
}

// ---------------- host launch ----------------
extern "C" void kernel_launch(void* const* d_in, const int* in_sizes, int n_in, void* d_out, int out_size,
                              void* d_ws, size_t ws_size, hipStream_t stream) {
    const float* W    = (const float*)d_in[0];
    const float* mask = (const float*)d_in[1];
    const int* src    = (const int*)d_in[2];
    const int* dst    = (const int*)d_in[3];
    const float* eps  = (const float*)d_in[4];
    const float* W1f  = (const float*)d_in[5];
    const float* b1f  = (const float*)d_in[6];
    const float* W1r  = (const float*)d_in[7];
    const float* b1r  = (const float*)d_in[8];
    const float* gam  = (const float*)d_in[9];
    const float* bet  = (const float*)d_in[10];
    const float* W2m  = (const float*)d_in[11];
    const float* b2m  = (const float*)d_in[12];
    const float* W2l  = (const float*)d_in[13];
    const float* b2l  = (const float*)d_in[14];
    float* out = (float*)d_out;

    // workspace layout
    ushort_t* Ha   = (ushort_t*)d_ws;          // 16,777,216
    ushort_t* Hb   = Ha + 16777216;            // 16,777,216
    ushort_t* w1t0 = Hb + 16777216;            // 4096
    ushort_t* w2lt = w1t0 + 4096;              // 8192
    ushort_t* w21t = w2lt + 8192;              // 49152
    float* bvec    = (float*)(w21t + 49152);   // 384
    float* sums    = bvec + 384;               // 4 layers x NSLOT x 256 = 16384
    int* order     = (int*)(sums + 16384);     // 2048
    int* irp       = order + 2048;             // 2049 (pad to 2052)
    int* icol      = irp + 2052;               // 16384

    mega_prep<<<64, 1024, 0, stream>>>(src, dst, W1f, W2l, b2m, W1r, W2m, irp, icol, order,
                                       w1t0, w2lt, bvec, w21t, sums);

    const int SL = NSLOT * 256;
    gin_mm1_l0<<<N_SUM, 256, 0, stream>>>(W, w1t0, b1f, eps, irp, icol, order, Ha, sums);
    gin_mm1_fused<<<N_SUM, 512, 0, stream>>>(Ha, w21t, b1r, bvec, sums, gam, bet, eps + 1,
                                             irp, icol, order, Hb, sums + SL);
    gin_mm1_fused<<<N_SUM, 512, 0, stream>>>(Hb, w21t + 16384, b1r + 128, bvec + 128, sums + SL,
                                             gam + 128, bet + 128, eps + 2, irp, icol, order, Ha, sums + 2 * SL);
    gin_mm1_fused<<<N_SUM, 512, 0, stream>>>(Ha, w21t + 32768, b1r + 256, bvec + 256, sums + 2 * SL,
                                             gam + 256, bet + 256, eps + 3, irp, icol, order, Hb, sums + 3 * SL);
    gin_mm2_last<<<N_SUM, 256, 0, stream>>>(Hb, w2lt, b2l, sums + 3 * SL, gam + 384, bet + 384, mask, out);
}

// Round 15
// 264.425 us; speedup vs baseline: 1.0402x; 1.0402x over previous
//
#include <hip/hip_runtime.h>

#define N_SUM 2048
#define HIDD 128
#define NEDGE 16384
#define ROWS (N_SUM * 64)
#define NSLOT 16

typedef short short8 __attribute__((ext_vector_type(8)));
typedef float floatx4 __attribute__((ext_vector_type(4)));
typedef unsigned int uint4n __attribute__((ext_vector_type(4)));
typedef unsigned short ushort_t;

__device__ __forceinline__ ushort_t f2bf(float f) {
    unsigned u = __builtin_bit_cast(unsigned, f);
    u += 0x7fffu + ((u >> 16) & 1u);   // RNE
    return (ushort_t)(u >> 16);
}
__device__ __forceinline__ float bf2f(ushort_t h) {
    return __builtin_bit_cast(float, (unsigned)h << 16);
}
__device__ __forceinline__ void unpack8(uint4 v, float* f) {
    f[0] = bf2f(v.x & 0xffff); f[1] = bf2f(v.x >> 16);
    f[2] = bf2f(v.y & 0xffff); f[3] = bf2f(v.y >> 16);
    f[4] = bf2f(v.z & 0xffff); f[5] = bf2f(v.z >> 16);
    f[6] = bf2f(v.w & 0xffff); f[7] = bf2f(v.w >> 16);
}
__device__ __forceinline__ uint4 pack8(const float* f) {
    uint4 v;
    v.x = f2bf(f[0]) | ((unsigned)f2bf(f[1]) << 16);
    v.y = f2bf(f[2]) | ((unsigned)f2bf(f[3]) << 16);
    v.z = f2bf(f[4]) | ((unsigned)f2bf(f[5]) << 16);
    v.w = f2bf(f[6]) | ((unsigned)f2bf(f[7]) << 16);
    return v;
}
__device__ __forceinline__ void nt_store16(const void* src, void* dst) {
    __builtin_nontemporal_store(*(const uint4n*)src, (uint4n*)dst);
}

// ---------------- mega prep (ONE dispatch, 64 blocks x 1024 threads) ----------------
// block 0      : full CSR build, latency-batched (16 loads/thread in flight)
// blocks 1..13 : w1t0 / w2lt / bvec
// blocks 14..61: w21t = W2m @ W1r (B-fragment layout)
// blocks 62..63: zero sums
__global__ __launch_bounds__(1024) void mega_prep(const int* __restrict__ src, const int* __restrict__ dst,
                                                  const float* __restrict__ W1f, const float* __restrict__ W2l,
                                                  const float* __restrict__ b2m, const float* __restrict__ W1r,
                                                  const float* __restrict__ W2m,
                                                  int* __restrict__ irp, int* __restrict__ icol,
                                                  ushort_t* __restrict__ w1t0, ushort_t* __restrict__ w2lt,
                                                  float* __restrict__ bvec, ushort_t* __restrict__ w21t,
                                                  float* __restrict__ sums) {
    __shared__ int sdeg[2048];
    __shared__ int scur[2048];
    __shared__ int red[1024];
    int tid = threadIdx.x, blk = blockIdx.x;

    if (blk == 0) {
        sdeg[tid] = 0;
        sdeg[tid + 1024] = 0;
        __syncthreads();
        int d[16];
#pragma unroll
        for (int q = 0; q < 16; q++) d[q] = dst[q * 1024 + tid];
#pragma unroll
        for (int q = 0; q < 16; q++) atomicAdd(&sdeg[d[q]], 1);
        __syncthreads();
        int a = sdeg[2 * tid], b = sdeg[2 * tid + 1];
        red[tid] = a + b;
        __syncthreads();
        for (int off = 1; off < 1024; off <<= 1) {
            int v = (tid >= off) ? red[tid - off] : 0;
            __syncthreads();
            red[tid] += v;
            __syncthreads();
        }
        int base = (tid == 0) ? 0 : red[tid - 1];
        irp[2 * tid] = base;
        irp[2 * tid + 1] = base + a;
        scur[2 * tid] = base;
        scur[2 * tid + 1] = base + a;
        if (tid == 1023) irp[2048] = red[1023];
        __syncthreads();
        int s[16];
#pragma unroll
        for (int q = 0; q < 16; q++) s[q] = src[q * 1024 + tid];
#pragma unroll
        for (int q = 0; q < 16; q++) {
            int pos = atomicAdd(&scur[d[q]], 1);
            icol[pos] = s[q];
        }
    } else if (blk <= 13) {
        int idx = (blk - 1) * 1024 + tid;
        if (idx < 4096) {
            int nn = idx >> 5, k = idx & 31;
            w1t0[idx] = f2bf(k < 16 ? W1f[k * 128 + nn] : 0.f);
        } else if (idx < 4096 + 8192) {
            int r = idx - 4096;
            int nn = r >> 7, k = r & 127;
            w2lt[r] = f2bf(W2l[k * 64 + nn]);
        } else if (idx < 4096 + 8192 + 384) {
            int r = idx - 12288;
            int lm = r >> 7, c = r & 127;
            float s = 0.f;
            for (int o = 0; o < 128; o++) s += b2m[lm * 128 + o] * W1r[(size_t)lm * 16384 + o * 128 + c];
            bvec[r] = s;
        }
    } else if (blk <= 61) {
        int idx = (blk - 14) * 1024 + tid;  // 49152 total
        int lm = idx >> 14, r = idx & 16383, i = r >> 7, c = r & 127;
        const float* w2row = W2m + (size_t)lm * 16384 + i * 128;
        const float* w1col = W1r + (size_t)lm * 16384 + c;
        float s = 0.f;
#pragma unroll 8
        for (int o = 0; o < 128; o++) s += w2row[o] * w1col[o * 128];
        w21t[(size_t)lm * 16384 + c * 128 + i] = f2bf(s);
    } else {
        int idx = (blk - 62) * 1024 + tid;  // 2048 threads x 8 = 16384
#pragma unroll
        for (int q = 0; q < 8; q++) sums[idx * 8 + q] = 0.f;
    }
}

// A-layout for a 64x128 (or 64x32) bf16 tile: elem(m, k) at ((k>>3)*64 + m)*8 + (k&7)

// ---------------- layer 0: gather fp32 W + MFMA (K=16 padded to 32) ----------------
// 4-deep branch-free ring over deg&~3 edges + short tail (state = 1 float4/slab, no spill at 256 thr)
__global__ __launch_bounds__(256, 4) void gin_mm1_l0(const float* __restrict__ Xf, const ushort_t* __restrict__ W1t,
                                                     const float* __restrict__ b1, const float* __restrict__ eps,
                                                     const int* __restrict__ rp, const int* __restrict__ colv,
                                                     ushort_t* __restrict__ H, float* __restrict__ sums) {
    __shared__ ushort_t Zs[64 * 128];  // 16 KB
    int tid = threadIdx.x, n = blockIdx.x;
    float ev = 1.0f + eps[0];
    int e0 = rp[n], e1 = rp[n + 1], deg = e1 - e0;
    const float4* X = (const float4*)Xf;

    float4 a, sf, q0, q1, q2, q3;
    sf = X[(size_t)n * 256 + tid];
    int deg4 = deg & ~3;
    if (deg4) {
        q0 = X[(size_t)colv[e0] * 256 + tid];
        q1 = X[(size_t)colv[e0 + 1] * 256 + tid];
        q2 = X[(size_t)colv[e0 + 2] * 256 + tid];
        q3 = X[(size_t)colv[e0 + 3] * 256 + tid];
    }
    a.x = sf.x * ev; a.y = sf.y * ev; a.z = sf.z * ev; a.w = sf.w * ev;
    auto addf4 = [&](const float4& v) {
        a.x += v.x; a.y += v.y; a.z += v.z; a.w += v.w;
    };
    if (deg4) {
        for (int i = 4; i < deg4; i += 4) {
            addf4(q0); q0 = X[(size_t)colv[e0 + i] * 256 + tid];
            addf4(q1); q1 = X[(size_t)colv[e0 + i + 1] * 256 + tid];
            addf4(q2); q2 = X[(size_t)colv[e0 + i + 2] * 256 + tid];
            addf4(q3); q3 = X[(size_t)colv[e0 + i + 3] * 256 + tid];
        }
        addf4(q0); addf4(q1); addf4(q2); addf4(q3);
    }
    int rem = deg - deg4;
    if (rem > 0) {
        q0 = X[(size_t)colv[e0 + deg4] * 256 + tid];
        if (rem > 1) q1 = X[(size_t)colv[e0 + deg4 + 1] * 256 + tid];
        if (rem > 2) q2 = X[(size_t)colv[e0 + deg4 + 2] * 256 + tid];
        addf4(q0);
        if (rem > 1) addf4(q1);
        if (rem > 2) addf4(q2);
    }

    {
        int m = tid >> 2, k0 = (tid & 3) * 4;
        int addr = ((k0 >> 3) * 64 + m) * 8 + (k0 & 7);
        uint2 pv;
        pv.x = f2bf(a.x) | ((unsigned)f2bf(a.y) << 16);
        pv.y = f2bf(a.z) | ((unsigned)f2bf(a.w) << 16);
        *(uint2*)&Zs[addr] = pv;
        *(uint2*)&Zs[1024 + tid * 4] = make_uint2(0u, 0u);
    }
    __syncthreads();

    int w = tid >> 6, lane = tid & 63, lg = lane >> 4, ln = lane & 15;
    floatx4 C[4][2];
#pragma unroll
    for (int mt = 0; mt < 4; mt++) { C[mt][0] = {0.f, 0.f, 0.f, 0.f}; C[mt][1] = {0.f, 0.f, 0.f, 0.f}; }

    {
        short8 B0 = *(const short8*)&W1t[(w * 32 + ln) * 32 + lg * 8];
        short8 B1 = *(const short8*)&W1t[(w * 32 + 16 + ln) * 32 + lg * 8];
#pragma unroll
        for (int mt = 0; mt < 4; mt++) {
            short8 A = *(const short8*)&Zs[(lg * 64 + mt * 16 + ln) * 8];
            C[mt][0] = __builtin_amdgcn_mfma_f32_16x16x32_bf16(A, B0, C[mt][0], 0, 0, 0);
            C[mt][1] = __builtin_amdgcn_mfma_f32_16x16x32_bf16(A, B1, C[mt][1], 0, 0, 0);
        }
    }

    float bsum[2], bsq[2];
    float bv[2] = {b1[w * 32 + ln], b1[w * 32 + 16 + ln]};
#pragma unroll
    for (int nt = 0; nt < 2; nt++) {
        float s = 0.f, s2 = 0.f;
#pragma unroll
        for (int mt = 0; mt < 4; mt++)
#pragma unroll
            for (int r = 0; r < 4; r++) {
                float v = C[mt][nt][r] + bv[nt];
                C[mt][nt][r] = v;
                s += v; s2 += v * v;
            }
        bsum[nt] = s; bsq[nt] = s2;
    }
#pragma unroll
    for (int nt = 0; nt < 2; nt++) {
        bsum[nt] += __shfl_xor(bsum[nt], 16, 64);
        bsum[nt] += __shfl_xor(bsum[nt], 32, 64);
        bsq[nt] += __shfl_xor(bsq[nt], 16, 64);
        bsq[nt] += __shfl_xor(bsq[nt], 32, 64);
    }
    if (lg == 0) {
        float* sl = sums + (n & (NSLOT - 1)) * 256;
        int c0 = w * 32 + ln;
        atomicAdd(&sl[c0], bsum[0]);
        atomicAdd(&sl[c0 + 16], bsum[1]);
        atomicAdd(&sl[128 + c0], bsq[0]);
        atomicAdd(&sl[128 + c0 + 16], bsq[1]);
    }
    __syncthreads();
#pragma unroll
    for (int nt = 0; nt < 2; nt++) {
        int colc = w * 32 + nt * 16 + ln;
        int base = (colc >> 3) * 512 + (colc & 7);
#pragma unroll
        for (int mt = 0; mt < 4; mt++)
#pragma unroll
            for (int r = 0; r < 4; r++) {
                int row = mt * 16 + lg * 4 + r;
                Zs[base + row * 8] = f2bf(C[mt][nt][r]);
            }
    }
    __syncthreads();
#pragma unroll
    for (int q = 0; q < 4; q++)
        nt_store16(&((const uint4*)Zs)[q * 256 + tid], &((uint4*)&H[(size_t)n * 8192])[q * 256 + tid]);
}

// ---------------- fused layers 1..3 (512 threads, scalar math, 2-deep pipeline) -- r11 form ----------------
__global__ __launch_bounds__(512, 4) void gin_mm1_fused(const ushort_t* __restrict__ Hin,
                                                        const ushort_t* __restrict__ W21t,
                                                        const float* __restrict__ b1, const float* __restrict__ bvec,
                                                        const float* __restrict__ sums_prev,
                                                        const float* __restrict__ gam_prev,
                                                        const float* __restrict__ bet_prev,
                                                        const float* __restrict__ epsp,
                                                        const int* __restrict__ rp, const int* __restrict__ colv,
                                                        ushort_t* __restrict__ Hout, float* __restrict__ sums_cur) {
    __shared__ ushort_t Zs[64 * 128];   // 16 KB
    __shared__ float scs_lds[256];      // 1 KB
    int tid = threadIdx.x, n = blockIdx.x;
    if (tid < 128) {
        float s = 0.f, s2 = 0.f;
#pragma unroll
        for (int k = 0; k < NSLOT; k++) {
            s += sums_prev[k * 256 + tid];
            s2 += sums_prev[k * 256 + 128 + tid];
        }
        float mean = s * (1.f / (float)ROWS);
        float var = s2 * (1.f / (float)ROWS) - mean * mean;
        float sc = gam_prev[tid] * rsqrtf(var + 1e-5f);
        scs_lds[tid] = sc;
        scs_lds[128 + tid] = bet_prev[tid] - mean * sc;
    }
    __syncthreads();

    unsigned scp[2][8];
#pragma unroll
    for (int q = 0; q < 2; q++) {
        int cb = ((q * 512 + tid) >> 6) * 8;
#pragma unroll
        for (int j = 0; j < 8; j++)
            scp[q][j] = ((unsigned)f2bf(scs_lds[cb + j])) | ((unsigned)f2bf(scs_lds[128 + cb + j]) << 16);
    }

    float ev = 1.0f + epsp[0];
    int e0 = rp[n], e1 = rp[n + 1], deg = e1 - e0;
    const uint4* X = (const uint4*)Hin;
    float acc[2][8];
    uint4 bufA[2], bufB[2];

    auto loadslab = [&](uint4* buf, int node) {
        const uint4* p = X + (size_t)node * 1024;
        buf[0] = p[tid];
        buf[1] = p[512 + tid];
    };
    auto addp = [&](const uint4* buf) {
#pragma unroll
        for (int q = 0; q < 2; q++) {
            float f[8]; unpack8(buf[q], f);
#pragma unroll
            for (int j = 0; j < 8; j++) {
                float sc = __builtin_bit_cast(float, scp[q][j] << 16);
                float sh = __builtin_bit_cast(float, scp[q][j] & 0xffff0000u);
                acc[q][j] += fmaxf(fmaf(f[j], sc, sh), 0.f);
            }
        }
    };

    loadslab(bufA, n);
    if (deg > 0) loadslab(bufB, colv[e0]);

#pragma unroll
    for (int q = 0; q < 2; q++) {
        float f[8]; unpack8(bufA[q], f);
#pragma unroll
        for (int j = 0; j < 8; j++) {
            float sc = __builtin_bit_cast(float, scp[q][j] << 16);
            float sh = __builtin_bit_cast(float, scp[q][j] & 0xffff0000u);
            acc[q][j] = ev * fmaxf(fmaf(f[j], sc, sh), 0.f);
        }
    }

    int i = 1;
    for (; i + 1 < deg; i += 2) {
        loadslab(bufA, colv[e0 + i]);
        addp(bufB);
        loadslab(bufB, colv[e0 + i + 1]);
        addp(bufA);
    }
    if (deg > 0) {
        if (i < deg) {
            loadslab(bufA, colv[e0 + i]);
            addp(bufB);
            addp(bufA);
        } else {
            addp(bufB);
        }
    }

#pragma unroll
    for (int q = 0; q < 2; q++) ((uint4*)Zs)[q * 512 + tid] = pack8(acc[q]);
    __syncthreads();

    int w = tid >> 6, lane = tid & 63, lg = lane >> 4, ln = lane & 15;
    floatx4 C[4];
#pragma unroll
    for (int mt = 0; mt < 4; mt++) C[mt] = {0.f, 0.f, 0.f, 0.f};

    for (int kb = 0; kb < 4; kb++) {
        short8 B = *(const short8*)&W21t[(w * 16 + ln) * 128 + kb * 32 + lg * 8];
#pragma unroll
        for (int mt = 0; mt < 4; mt++) {
            short8 A = *(const short8*)&Zs[((kb * 4 + lg) * 64 + mt * 16 + ln) * 8];
            C[mt] = __builtin_amdgcn_mfma_f32_16x16x32_bf16(A, B, C[mt], 0, 0, 0);
        }
    }

    float fac = ev + (float)deg;
    int c0 = w * 16 + ln;
    float bv = b1[c0] + fac * bvec[c0];
    float s = 0.f, s2 = 0.f;
#pragma unroll
    for (int mt = 0; mt < 4; mt++)
#pragma unroll
        for (int r = 0; r < 4; r++) {
            float v = C[mt][r] + bv;
            C[mt][r] = v;
            s += v; s2 += v * v;
        }
    s += __shfl_xor(s, 16, 64);
    s += __shfl_xor(s, 32, 64);
    s2 += __shfl_xor(s2, 16, 64);
    s2 += __shfl_xor(s2, 32, 64);
    if (lg == 0) {
        float* sl = sums_cur + (n & (NSLOT - 1)) * 256;
        atomicAdd(&sl[c0], s);
        atomicAdd(&sl[128 + c0], s2);
    }

    __syncthreads();
    {
        int base = (c0 >> 3) * 512 + (c0 & 7);
#pragma unroll
        for (int mt = 0; mt < 4; mt++)
#pragma unroll
            for (int r = 0; r < 4; r++) {
                int row = mt * 16 + lg * 4 + r;
                Zs[base + row * 8] = f2bf(C[mt][r]);
            }
    }
    __syncthreads();
#pragma unroll
    for (int q = 0; q < 2; q++)
        nt_store16(&((const uint4*)Zs)[q * 512 + tid], &((uint4*)&Hout[(size_t)n * 8192])[q * 512 + tid]);
}

// ---------------- final: PE = sum_rows mask * (relu(bn(H3)) @ W2l + b2l) ----------------
__global__ __launch_bounds__(256, 4) void gin_mm2_last(const ushort_t* __restrict__ H, const ushort_t* __restrict__ W2t,
                                                       const float* __restrict__ b2,
                                                       const float* __restrict__ sums_prev,
                                                       const float* __restrict__ gam_prev,
                                                       const float* __restrict__ bet_prev,
                                                       const float* __restrict__ mask, float* __restrict__ out) {
    __shared__ ushort_t Hs[64 * 128];
    __shared__ float scs_lds[256];
    int tid = threadIdx.x, n = blockIdx.x;
    if (tid < 128) {
        float s = 0.f, s2 = 0.f;
#pragma unroll
        for (int k = 0; k < NSLOT; k++) {
            s += sums_prev[k * 256 + tid];
            s2 += sums_prev[k * 256 + 128 + tid];
        }
        float mean = s * (1.f / (float)ROWS);
        float var = s2 * (1.f / (float)ROWS) - mean * mean;
        float sc = gam_prev[tid] * rsqrtf(var + 1e-5f);
        scs_lds[tid] = sc;
        scs_lds[128 + tid] = bet_prev[tid] - mean * sc;
    }
    __syncthreads();

#pragma unroll
    for (int q = 0; q < 4; q++) {
        int c = q * 256 + tid;
        uint4 v = ((const uint4*)&H[(size_t)n * 8192])[c];
        float f[8]; unpack8(v, f);
        int cb = (c >> 6) * 8;
#pragma unroll
        for (int j = 0; j < 8; j++) f[j] = fmaxf(fmaf(f[j], scs_lds[cb + j], scs_lds[128 + cb + j]), 0.f);
        ((uint4*)Hs)[c] = pack8(f);
    }
    __syncthreads();

    int w = tid >> 6, lane = tid & 63, lg = lane >> 4, ln = lane & 15;
    floatx4 C[4];
#pragma unroll
    for (int mt = 0; mt < 4; mt++) C[mt] = {0.f, 0.f, 0.f, 0.f};

    for (int kb = 0; kb < 4; kb++) {
        short8 B = *(const short8*)&W2t[(w * 16 + ln) * 128 + kb * 32 + lg * 8];
#pragma unroll
        for (int mt = 0; mt < 4; mt++) {
            short8 A = *(const short8*)&Hs[((kb * 4 + lg) * 64 + mt * 16 + ln) * 8];
            C[mt] = __builtin_amdgcn_mfma_f32_16x16x32_bf16(A, B, C[mt], 0, 0, 0);
        }
    }

    int colc = w * 16 + ln;
    float bb = b2[colc];
    float pe = 0.f;
#pragma unroll
    for (int mt = 0; mt < 4; mt++)
#pragma unroll
        for (int r = 0; r < 4; r++) {
            int row = mt * 16 + lg * 4 + r;
            pe += mask[n * 64 + row] * (C[mt][r] + bb);
        }
    pe += __shfl_xor(pe, 16, 64);
    pe += __shfl_xor(pe, 32, 64);
    if (lg == 0) out[(size_t)n * 64 + colc] = pe;
}

// ---------------- host launch ----------------
extern "C" void kernel_launch(void* const* d_in, const int* in_sizes, int n_in, void* d_out, int out_size,
                              void* d_ws, size_t ws_size, hipStream_t stream) {
    const float* W    = (const float*)d_in[0];
    const float* mask = (const float*)d_in[1];
    const int* src    = (const int*)d_in[2];
    const int* dst    = (const int*)d_in[3];
    const float* eps  = (const float*)d_in[4];
    const float* W1f  = (const float*)d_in[5];
    const float* b1f  = (const float*)d_in[6];
    const float* W1r  = (const float*)d_in[7];
    const float* b1r  = (const float*)d_in[8];
    const float* gam  = (const float*)d_in[9];
    const float* bet  = (const float*)d_in[10];
    const float* W2m  = (const float*)d_in[11];
    const float* b2m  = (const float*)d_in[12];
    const float* W2l  = (const float*)d_in[13];
    const float* b2l  = (const float*)d_in[14];
    float* out = (float*)d_out;

    // workspace layout
    ushort_t* Ha   = (ushort_t*)d_ws;          // 16,777,216
    ushort_t* Hb   = Ha + 16777216;            // 16,777,216
    ushort_t* w1t0 = Hb + 16777216;            // 4096
    ushort_t* w2lt = w1t0 + 4096;              // 8192
    ushort_t* w21t = w2lt + 8192;              // 49152
    float* bvec    = (float*)(w21t + 49152);   // 384
    float* sums    = bvec + 384;               // 4 layers x NSLOT x 256 = 16384
    int* irp       = (int*)(sums + 16384);     // 2049 (pad to 2052)
    int* icol      = irp + 2052;               // 16384

    mega_prep<<<64, 1024, 0, stream>>>(src, dst, W1f, W2l, b2m, W1r, W2m, irp, icol,
                                       w1t0, w2lt, bvec, w21t, sums);

    const int SL = NSLOT * 256;
    gin_mm1_l0<<<N_SUM, 256, 0, stream>>>(W, w1t0, b1f, eps, irp, icol, Ha, sums);
    gin_mm1_fused<<<N_SUM, 512, 0, stream>>>(Ha, w21t, b1r, bvec, sums, gam, bet, eps + 1,
                                             irp, icol, Hb, sums + SL);
    gin_mm1_fused<<<N_SUM, 512, 0, stream>>>(Hb, w21t + 16384, b1r + 128, bvec + 128, sums + SL,
                                             gam + 128, bet + 128, eps + 2, irp, icol, Ha, sums + 2 * SL);
    gin_mm1_fused<<<N_SUM, 512, 0, stream>>>(Ha, w21t + 32768, b1r + 256, bvec + 256, sums + 2 * SL,
                                             gam + 256, bet + 256, eps + 3, irp, icol, Hb, sums + 3 * SL);
    gin_mm2_last<<<N_SUM, 256, 0, stream>>>(Hb, w2lt, b2l, sums + 3 * SL, gam + 384, bet + 384, mask, out);
}